// Round 1
// baseline (1232.505 us; speedup 1.0000x reference)
//
#include <hip/hip_runtime.h>

// ---------------- problem constants ----------------
#define NTOK   32768
#define DIM    512
#define NCODE  4096
#define NELEM  (NTOK*DIM)          // 16777216
#define COMMIT 0.25

// ---------------- ws layout (bytes) ----------------
#define OFF_ZB      0ULL                 // bf16 z: 32768*512*2 = 33554432
#define OFF_EB      33554432ULL          // bf16 emb: 4096*512*2 = 4194304
#define OFF_EN64    37748736ULL          // double[4096]
#define OFF_EN32    37781504ULL          // float[4096]
#define OFF_ROWMIN  37797888ULL          // u64[32768]  (packed f32key|code)
#define OFF_ROWKEY  38060032ULL          // u64[32768]  (sortable f64 key)
#define OFF_ROWIDX  38322176ULL          // u32[32768]
#define OFF_COUNTS  38453248ULL          // u32[4096]
#define OFF_MISC    38469632ULL          // sse double @+0, gcount u32 @+8
#define OFF_LIST    38469888ULL          // Cand[524288] = 8388608
#define LIST_CAP    524288u

#define MARGIN 1e-3f   // >> worst-case bf16 score error (~3e-4); gap scale 1.6e-3

struct Cand { unsigned row, code; unsigned long long key; };

typedef __bf16 bf16x8 __attribute__((ext_vector_type(8)));
typedef float  floatx4 __attribute__((ext_vector_type(4)));

// ---------------- helpers ----------------
__device__ __forceinline__ unsigned short f2bf(float f) {
    unsigned u = __float_as_uint(f);
    u += 0x7FFFu + ((u >> 16) & 1u);   // RNE
    return (unsigned short)(u >> 16);
}
__device__ __forceinline__ unsigned f2key(float f) {   // order-preserving f32 -> u32
    unsigned u = __float_as_uint(f);
    return (u & 0x80000000u) ? ~u : (u | 0x80000000u);
}
__device__ __forceinline__ float key2f(unsigned k) {
    unsigned u = (k & 0x80000000u) ? (k ^ 0x80000000u) : ~k;
    return __uint_as_float(u);
}
__device__ __forceinline__ unsigned long long d2key(double d) { // order-preserving f64 -> u64
    unsigned long long u = __double_as_longlong(d);
    return (u & 0x8000000000000000ULL) ? ~u : (u | 0x8000000000000000ULL);
}

// ---------------- 1. fp32 -> bf16 conversion ----------------
__global__ void conv_kernel(const float* __restrict__ z, const float* __restrict__ e,
                            unsigned short* __restrict__ zb, unsigned short* __restrict__ eb) {
    const int ZF4 = NELEM / 4;            // 4194304
    const int TF4 = ZF4 + (NCODE*DIM)/4;  // + 524288
    int i = blockIdx.x * blockDim.x + threadIdx.x;
    if (i >= TF4) return;
    const float4* src; unsigned short* dst; int j;
    if (i < ZF4) { src = (const float4*)z; dst = zb; j = i; }
    else         { src = (const float4*)e; dst = eb; j = i - ZF4; }
    float4 v = src[j];
    ushort4 o; o.x = f2bf(v.x); o.y = f2bf(v.y); o.z = f2bf(v.z); o.w = f2bf(v.w);
    ((ushort4*)dst)[j] = o;
}

// ---------------- 2. ||e_k||^2 (f64 + f32) ----------------
__global__ void enorm_kernel(const float* __restrict__ emb,
                             double* __restrict__ en64, float* __restrict__ en32) {
    int gw = (blockIdx.x * blockDim.x + threadIdx.x) >> 6;   // wave id = code
    int lane = threadIdx.x & 63;
    if (gw >= NCODE) return;
    const float4* p = (const float4*)(emb + (size_t)gw * DIM);
    float4 a = p[lane * 2], b = p[lane * 2 + 1];
    double s = (double)a.x*a.x + (double)a.y*a.y + (double)a.z*a.z + (double)a.w*a.w
             + (double)b.x*b.x + (double)b.y*b.y + (double)b.z*b.z + (double)b.w*b.w;
    for (int off = 32; off; off >>= 1) s += __shfl_down(s, off);
    if (lane == 0) { en64[gw] = s; en32[gw] = (float)s; }
}

// ---------------- 3. MFMA score pass (PASS 0: rowmin, PASS 1: candidates) ------
// tile 128x128, BK=64, 4 waves in 2x2, each wave 4x4 of 16x16x32 MFMAs.
#define LDK 72   // 64 + 8 pad: ds_read_b128 fragment reads -> 2-way (free) conflicts
template <int PASS>
__global__ __launch_bounds__(256)
void score_pass(const unsigned short* __restrict__ zb, const unsigned short* __restrict__ eb,
                const float* __restrict__ en32,
                unsigned long long* __restrict__ rowmin,
                unsigned* __restrict__ gcount, Cand* __restrict__ list) {
    __shared__ unsigned short sA[128 * LDK];
    __shared__ unsigned short sB[128 * LDK];
    const int tid = threadIdx.x;
    const int row0 = blockIdx.x * 128;   // token tile
    const int col0 = blockIdx.y * 128;   // code tile
    const int wave = tid >> 6, lane = tid & 63;
    const int wm = wave >> 1, wn = wave & 1;
    const int l15 = lane & 15, quad = lane >> 4;

    floatx4 acc[4][4] = {};

    for (int ks = 0; ks < DIM; ks += 64) {
        __syncthreads();
#pragma unroll
        for (int r = 0; r < 4; r++) {                // 1024 16B chunks each
            int c = tid + 256 * r;
            int rr = c >> 3, cc = (c & 7) << 3;
            *(uint4*)(&sA[rr * LDK + cc]) = *(const uint4*)(&zb[(row0 + rr) * DIM + ks + cc]);
            *(uint4*)(&sB[rr * LDK + cc]) = *(const uint4*)(&eb[(col0 + rr) * DIM + ks + cc]);
        }
        __syncthreads();
#pragma unroll
        for (int kk = 0; kk < 2; kk++) {
            bf16x8 af[4], bfr[4];
#pragma unroll
            for (int i = 0; i < 4; i++) {
                int m = wm * 64 + i * 16 + l15;      // A[m][k]: m=lane&15, k=quad*8+j
                af[i]  = *(const bf16x8*)(&sA[m * LDK + kk * 32 + quad * 8]);
                int n = wn * 64 + i * 16 + l15;      // B[k][n]: n=lane&15, k=quad*8+j
                bfr[i] = *(const bf16x8*)(&sB[n * LDK + kk * 32 + quad * 8]);
            }
#pragma unroll
            for (int i = 0; i < 4; i++)
#pragma unroll
                for (int j = 0; j < 4; j++)
                    acc[i][j] = __builtin_amdgcn_mfma_f32_16x16x32_bf16(af[i], bfr[j], acc[i][j], 0, 0, 0);
        }
    }

    // C/D layout: col = lane&15, row = quad*4 + reg  [verified m89/m91]
    if (PASS == 0) {
#pragma unroll
        for (int i = 0; i < 4; i++) {
#pragma unroll
            for (int reg = 0; reg < 4; reg++) {
                unsigned long long best = ~0ULL;
#pragma unroll
                for (int j = 0; j < 4; j++) {
                    int n = col0 + wn * 64 + j * 16 + l15;
                    float s = en32[n] - 2.0f * acc[i][j][reg];
                    unsigned long long p = ((unsigned long long)f2key(s) << 32) | (unsigned)n;
                    best = best < p ? best : p;
                }
#pragma unroll
                for (int off = 1; off < 16; off <<= 1) {
                    unsigned long long o = __shfl_xor(best, off);
                    best = best < o ? best : o;
                }
                if (l15 == 0) {
                    int m = row0 + wm * 64 + i * 16 + quad * 4 + reg;
                    atomicMin(&rowmin[m], best);
                }
            }
        }
    } else {
#pragma unroll
        for (int i = 0; i < 4; i++) {
#pragma unroll
            for (int reg = 0; reg < 4; reg++) {
                int m = row0 + wm * 64 + i * 16 + quad * 4 + reg;
                float rm = key2f((unsigned)(rowmin[m] >> 32)) + MARGIN;
#pragma unroll
                for (int j = 0; j < 4; j++) {
                    int n = col0 + wn * 64 + j * 16 + l15;
                    float s = en32[n] - 2.0f * acc[i][j][reg];
                    if (s <= rm) {
                        unsigned pos = atomicAdd(gcount, 1u);
                        if (pos < LIST_CAP) { list[pos].row = (unsigned)m; list[pos].code = (unsigned)n; }
                    }
                }
            }
        }
    }
}

// ---------------- 4. exact fp64 refine: C1 keys, C2 index -------------
__global__ void refine1(const float* __restrict__ z, const float* __restrict__ emb,
                        const double* __restrict__ en64,
                        Cand* __restrict__ list, const unsigned* __restrict__ gcount,
                        unsigned long long* __restrict__ rowkey) {
    unsigned n = *gcount; if (n > LIST_CAP) n = LIST_CAP;
    unsigned gw = (blockIdx.x * blockDim.x + threadIdx.x) >> 6;
    unsigned nw = (gridDim.x * blockDim.x) >> 6;
    int lane = threadIdx.x & 63;
    for (unsigned c = gw; c < n; c += nw) {
        unsigned row = list[c].row, code = list[c].code;
        const float4* zp = (const float4*)(z + (size_t)row * DIM);
        const float4* ep = (const float4*)(emb + (size_t)code * DIM);
        float4 a0 = zp[lane * 2], a1 = zp[lane * 2 + 1];
        float4 b0 = ep[lane * 2], b1 = ep[lane * 2 + 1];
        double d = (double)a0.x*b0.x + (double)a0.y*b0.y + (double)a0.z*b0.z + (double)a0.w*b0.w
                 + (double)a1.x*b1.x + (double)a1.y*b1.y + (double)a1.z*b1.z + (double)a1.w*b1.w;
        for (int off = 32; off; off >>= 1) d += __shfl_down(d, off);
        if (lane == 0) {
            unsigned long long k = d2key(en64[code] - 2.0 * d);
            list[c].key = k;
            atomicMin(&rowkey[row], k);
        }
    }
}

__global__ void refine2(const Cand* __restrict__ list, const unsigned* __restrict__ gcount,
                        const unsigned long long* __restrict__ rowkey,
                        unsigned* __restrict__ rowidx) {
    unsigned n = *gcount; if (n > LIST_CAP) n = LIST_CAP;
    unsigned t = blockIdx.x * blockDim.x + threadIdx.x;
    unsigned nt = gridDim.x * blockDim.x;
    for (unsigned c = t; c < n; c += nt)
        if (list[c].key == rowkey[list[c].row])
            atomicMin(&rowidx[list[c].row], list[c].code);   // tie -> smallest idx (argmin semantics)
}

// ---------------- 5. gather + STE output + sse -------------
__global__ void gather_loss(const float* __restrict__ z, const float* __restrict__ emb,
                            const unsigned* __restrict__ rowidx,
                            float* __restrict__ out, double* __restrict__ sse) {
    int i = blockIdx.x * blockDim.x + threadIdx.x;   // f4 index, 4194304 total
    float4 zv = ((const float4*)z)[i];
    int row = i >> 7, col = i & 127;
    unsigned code = rowidx[row];
    float4 q = ((const float4*)emb)[code * 128 + col];
    float4 dv = make_float4(q.x - zv.x, q.y - zv.y, q.z - zv.z, q.w - zv.w);
    float4 o  = make_float4(zv.x + dv.x, zv.y + dv.y, zv.z + dv.z, zv.w + dv.w);
    ((float4*)out)[i] = o;
    double loc = (double)dv.x*dv.x + (double)dv.y*dv.y + (double)dv.z*dv.z + (double)dv.w*dv.w;
    for (int off = 32; off; off >>= 1) loc += __shfl_down(loc, off);
    __shared__ double sw[4];
    if ((threadIdx.x & 63) == 0) sw[threadIdx.x >> 6] = loc;
    __syncthreads();
    if (threadIdx.x == 0) atomicAdd(sse, sw[0] + sw[1] + sw[2] + sw[3]);
}

__global__ void hist_kernel(const unsigned* __restrict__ rowidx, unsigned* __restrict__ counts) {
    int r = blockIdx.x * blockDim.x + threadIdx.x;
    if (r < NTOK) atomicAdd(&counts[rowidx[r]], 1u);
}

// ---------------- 6. losses + perplexity -------------
__global__ void finalize(const unsigned* __restrict__ counts, const double* __restrict__ sse,
                         float* __restrict__ out) {
    __shared__ double sh[256];
    double h = 0.0;
    for (int b = threadIdx.x; b < NCODE; b += 256) {
        double p = (double)counts[b] / (double)NTOK;
        h += p * log(p + 1e-10);
    }
    sh[threadIdx.x] = h;
    __syncthreads();
    for (int off = 128; off > 0; off >>= 1) {
        if (threadIdx.x < off) sh[threadIdx.x] += sh[threadIdx.x + off];
        __syncthreads();
    }
    if (threadIdx.x == 0) {
        out[NELEM]     = (float)((1.0 + COMMIT) * (*sse) / (double)NELEM);  // vq_loss
        out[NELEM + 1] = (float)exp(-sh[0]);                                 // perplexity
    }
}

// ---------------- launch ----------------
extern "C" void kernel_launch(void* const* d_in, const int* in_sizes, int n_in,
                              void* d_out, int out_size, void* d_ws, size_t ws_size,
                              hipStream_t stream) {
    const float* z   = (const float*)d_in[0];
    const float* emb = (const float*)d_in[1];
    float* out = (float*)d_out;
    char* ws = (char*)d_ws;

    unsigned short* zb = (unsigned short*)(ws + OFF_ZB);
    unsigned short* eb = (unsigned short*)(ws + OFF_EB);
    double*   en64   = (double*)(ws + OFF_EN64);
    float*    en32   = (float*)(ws + OFF_EN32);
    unsigned long long* rowmin = (unsigned long long*)(ws + OFF_ROWMIN);
    unsigned long long* rowkey = (unsigned long long*)(ws + OFF_ROWKEY);
    unsigned* rowidx = (unsigned*)(ws + OFF_ROWIDX);
    unsigned* counts = (unsigned*)(ws + OFF_COUNTS);
    double*   sse    = (double*)(ws + OFF_MISC);
    unsigned* gcount = (unsigned*)(ws + OFF_MISC + 8);
    Cand*     list   = (Cand*)(ws + OFF_LIST);

    // init: rowmin|rowkey|rowidx -> 0xFF (u64/u32 max); counts|sse|gcount -> 0
    hipMemsetAsync(ws + OFF_ROWMIN, 0xFF, 262144 + 262144 + 131072, stream);
    hipMemsetAsync(ws + OFF_COUNTS, 0x00, 16384 + 256, stream);

    conv_kernel<<<(NELEM/4 + (NCODE*DIM)/4 + 255) / 256, 256, 0, stream>>>(z, emb, zb, eb);
    enorm_kernel<<<(NCODE * 64) / 256, 256, 0, stream>>>(emb, en64, en32);

    dim3 g(NTOK / 128, NCODE / 128);   // 256 x 32
    score_pass<0><<<g, 256, 0, stream>>>(zb, eb, en32, rowmin, gcount, list);
    score_pass<1><<<g, 256, 0, stream>>>(zb, eb, en32, rowmin, gcount, list);

    refine1<<<1024, 256, 0, stream>>>(z, emb, en64, list, gcount, rowkey);
    refine2<<<256, 256, 0, stream>>>(list, gcount, rowkey, rowidx);

    gather_loss<<<NELEM / 4 / 256, 256, 0, stream>>>(z, emb, rowidx, out, sse);
    hist_kernel<<<NTOK / 256, 256, 0, stream>>>(rowidx, counts);
    finalize<<<1, 256, 0, stream>>>(counts, sse, out);
}

// Round 2
// 617.029 us; speedup vs baseline: 1.9975x; 1.9975x over previous
//
#include <hip/hip_runtime.h>

// ---------------- problem constants ----------------
#define NTOK   32768
#define DIM    512
#define NCODE  4096
#define NELEM  (NTOK*DIM)          // 16777216
#define COMMIT 0.25

// ---------------- ws layout (bytes) ----------------
#define OFF_ZB      0ULL                 // bf16 z: 32768*512*2 = 33554432
#define OFF_EB      33554432ULL          // bf16 emb: 4096*512*2 = 4194304
#define OFF_EN32    37748736ULL          // float[4096]
#define OFF_ROWMIN  37765120ULL          // u64[32768]  (packed f32key|code)
#define OFF_COUNTS  38027264ULL          // u32[4096]
#define OFF_MISC    38043648ULL          // sse double @+0

typedef __bf16 bf16x8 __attribute__((ext_vector_type(8)));
typedef float  floatx4 __attribute__((ext_vector_type(4)));

#define GLOBAL_AS __attribute__((address_space(1)))
#define LDS_AS    __attribute__((address_space(3)))

// ---------------- helpers ----------------
__device__ __forceinline__ unsigned short f2bf(float f) {
    unsigned u = __float_as_uint(f);
    u += 0x7FFFu + ((u >> 16) & 1u);   // RNE
    return (unsigned short)(u >> 16);
}
__device__ __forceinline__ unsigned f2key(float f) {   // order-preserving f32 -> u32
    unsigned u = __float_as_uint(f);
    return (u & 0x80000000u) ? ~u : (u | 0x80000000u);
}
__device__ __forceinline__ void gld16(const void* g, void* l) {
    // async global->LDS, 16B/lane; LDS dest = wave-uniform base + lane*16
    __builtin_amdgcn_global_load_lds((const GLOBAL_AS unsigned int*)g,
                                     (LDS_AS unsigned int*)l, 16, 0, 0);
}

// ---------------- 1. fp32 -> bf16 conversion ----------------
__global__ void conv_kernel(const float* __restrict__ z, const float* __restrict__ e,
                            unsigned short* __restrict__ zb, unsigned short* __restrict__ eb) {
    const int ZF4 = NELEM / 4;            // 4194304
    const int TF4 = ZF4 + (NCODE*DIM)/4;  // + 524288
    int i = blockIdx.x * blockDim.x + threadIdx.x;
    if (i >= TF4) return;
    const float4* src; unsigned short* dst; int j;
    if (i < ZF4) { src = (const float4*)z; dst = zb; j = i; }
    else         { src = (const float4*)e; dst = eb; j = i - ZF4; }
    float4 v = src[j];
    ushort4 o; o.x = f2bf(v.x); o.y = f2bf(v.y); o.z = f2bf(v.z); o.w = f2bf(v.w);
    ((ushort4*)dst)[j] = o;
}

// ---------------- 2. ||e_k||^2 (f32, double-accumulated) ----------------
__global__ void enorm_kernel(const float* __restrict__ emb, float* __restrict__ en32) {
    int gw = (blockIdx.x * blockDim.x + threadIdx.x) >> 6;   // wave id = code
    int lane = threadIdx.x & 63;
    if (gw >= NCODE) return;
    const float4* p = (const float4*)(emb + (size_t)gw * DIM);
    float4 a = p[lane * 2], b = p[lane * 2 + 1];
    double s = (double)a.x*a.x + (double)a.y*a.y + (double)a.z*a.z + (double)a.w*a.w
             + (double)b.x*b.x + (double)b.y*b.y + (double)b.z*b.z + (double)b.w*b.w;
    for (int off = 32; off; off >>= 1) s += __shfl_down(s, off);
    if (lane == 0) en32[gw] = (float)s;
}

// ---------------- 3. single MFMA score pass -> packed rowmin ----------------
// tile 128x128, BK=64, 4 waves 2x2, each wave 4x4 of 16x16x32 MFMAs.
// LDS unpadded [128][64] shorts (required by global_load_lds lane-scatter rule).
__global__ __launch_bounds__(256)
void score_pass(const unsigned short* __restrict__ zb, const unsigned short* __restrict__ eb,
                const float* __restrict__ en32,
                unsigned long long* __restrict__ rowmin) {
    __shared__ unsigned short sA[128 * 64];
    __shared__ unsigned short sB[128 * 64];
    const int tid = threadIdx.x;
    const int row0 = blockIdx.x * 128;   // token tile
    const int col0 = blockIdx.y * 128;   // code tile
    const int wv = tid >> 6, ln = tid & 63;
    const int wm = wv >> 1, wn = wv & 1;
    const int l15 = ln & 15, quad = ln >> 4;

    floatx4 acc[4][4] = {};

    const int lrow = ln >> 3;            // lane's row within an 8-row chunk
    const int lcol = (ln & 7) * 16;      // lane's byte offset within 128B k-slice

    for (int ks = 0; ks < DIM; ks += 64) {
        __syncthreads();                 // previous iter's ds_reads done
#pragma unroll
        for (int r = 0; r < 4; r++) {
            int ch = wv * 4 + r;         // 0..15, wave-uniform
            int rowA = ch * 8 + lrow;    // 0..127
            gld16((const char*)&zb[(size_t)(row0 + rowA) * DIM + ks] + lcol,
                  (char*)&sA[ch * 512]);
            gld16((const char*)&eb[(size_t)(col0 + rowA) * DIM + ks] + lcol,
                  (char*)&sB[ch * 512]);
        }
        __syncthreads();                 // vmcnt drained before barrier -> loads landed
#pragma unroll
        for (int kk = 0; kk < 2; kk++) {
            bf16x8 af[4], bfr[4];
#pragma unroll
            for (int i = 0; i < 4; i++) {
                int m = wm * 64 + i * 16 + l15;      // A[m][k]: m=lane&15, k=quad*8+j
                af[i]  = *(const bf16x8*)(&sA[m * 64 + kk * 32 + quad * 8]);
                int n = wn * 64 + i * 16 + l15;      // B[k][n]: n=lane&15, k=quad*8+j
                bfr[i] = *(const bf16x8*)(&sB[n * 64 + kk * 32 + quad * 8]);
            }
#pragma unroll
            for (int i = 0; i < 4; i++)
#pragma unroll
                for (int j = 0; j < 4; j++)
                    acc[i][j] = __builtin_amdgcn_mfma_f32_16x16x32_bf16(af[i], bfr[j], acc[i][j], 0, 0, 0);
        }
    }

    // C/D layout: col = lane&15, row = quad*4 + reg  [verified m89/m91]
#pragma unroll
    for (int i = 0; i < 4; i++) {
#pragma unroll
        for (int reg = 0; reg < 4; reg++) {
            unsigned long long best = ~0ULL;
#pragma unroll
            for (int j = 0; j < 4; j++) {
                int n = col0 + wn * 64 + j * 16 + l15;
                float s = en32[n] - 2.0f * acc[i][j][reg];
                unsigned long long p = ((unsigned long long)f2key(s) << 32) | (unsigned)n;
                best = best < p ? best : p;
            }
#pragma unroll
            for (int off = 1; off < 16; off <<= 1) {
                unsigned long long o = __shfl_xor(best, off);
                best = best < o ? best : o;
            }
            if (l15 == 0) {
                int m = row0 + wm * 64 + i * 16 + quad * 4 + reg;
                atomicMin(&rowmin[m], best);
            }
        }
    }
}

// ---------------- 4. gather + STE output + sse -------------
__global__ void gather_loss(const float* __restrict__ z, const float* __restrict__ emb,
                            const unsigned long long* __restrict__ rowmin,
                            float* __restrict__ out, double* __restrict__ sse) {
    int i = blockIdx.x * blockDim.x + threadIdx.x;   // f4 index, 4194304 total
    float4 zv = ((const float4*)z)[i];
    int row = i >> 7, col = i & 127;
    unsigned code = (unsigned)(rowmin[row] & 0xFFFFFFFFULL);
    float4 q = ((const float4*)emb)[code * 128 + col];
    float4 dv = make_float4(q.x - zv.x, q.y - zv.y, q.z - zv.z, q.w - zv.w);
    float4 o  = make_float4(zv.x + dv.x, zv.y + dv.y, zv.z + dv.z, zv.w + dv.w);
    ((float4*)out)[i] = o;
    double loc = (double)dv.x*dv.x + (double)dv.y*dv.y + (double)dv.z*dv.z + (double)dv.w*dv.w;
    for (int off = 32; off; off >>= 1) loc += __shfl_down(loc, off);
    __shared__ double sw[4];
    if ((threadIdx.x & 63) == 0) sw[threadIdx.x >> 6] = loc;
    __syncthreads();
    if (threadIdx.x == 0) atomicAdd(sse, sw[0] + sw[1] + sw[2] + sw[3]);
}

__global__ void hist_kernel(const unsigned long long* __restrict__ rowmin,
                            unsigned* __restrict__ counts) {
    int r = blockIdx.x * blockDim.x + threadIdx.x;
    if (r < NTOK) atomicAdd(&counts[(unsigned)(rowmin[r] & 0xFFFFFFFFULL)], 1u);
}

// ---------------- 5. losses + perplexity -------------
__global__ void finalize(const unsigned* __restrict__ counts, const double* __restrict__ sse,
                         float* __restrict__ out) {
    __shared__ double sh[256];
    double h = 0.0;
    for (int b = threadIdx.x; b < NCODE; b += 256) {
        double p = (double)counts[b] / (double)NTOK;
        h += p * log(p + 1e-10);
    }
    sh[threadIdx.x] = h;
    __syncthreads();
    for (int off = 128; off > 0; off >>= 1) {
        if (threadIdx.x < off) sh[threadIdx.x] += sh[threadIdx.x + off];
        __syncthreads();
    }
    if (threadIdx.x == 0) {
        out[NELEM]     = (float)((1.0 + COMMIT) * (*sse) / (double)NELEM);  // vq_loss
        out[NELEM + 1] = (float)exp(-sh[0]);                                 // perplexity
    }
}

// ---------------- launch ----------------
extern "C" void kernel_launch(void* const* d_in, const int* in_sizes, int n_in,
                              void* d_out, int out_size, void* d_ws, size_t ws_size,
                              hipStream_t stream) {
    const float* z   = (const float*)d_in[0];
    const float* emb = (const float*)d_in[1];
    float* out = (float*)d_out;
    char* ws = (char*)d_ws;

    unsigned short* zb = (unsigned short*)(ws + OFF_ZB);
    unsigned short* eb = (unsigned short*)(ws + OFF_EB);
    float*    en32   = (float*)(ws + OFF_EN32);
    unsigned long long* rowmin = (unsigned long long*)(ws + OFF_ROWMIN);
    unsigned* counts = (unsigned*)(ws + OFF_COUNTS);
    double*   sse    = (double*)(ws + OFF_MISC);

    // init: rowmin -> 0xFF (u64 max); counts & sse -> 0
    hipMemsetAsync(ws + OFF_ROWMIN, 0xFF, 262144, stream);
    hipMemsetAsync(ws + OFF_COUNTS, 0x00, 16384 + 16, stream);

    conv_kernel<<<(NELEM/4 + (NCODE*DIM)/4 + 255) / 256, 256, 0, stream>>>(z, emb, zb, eb);
    enorm_kernel<<<(NCODE * 64) / 256, 256, 0, stream>>>(emb, en32);

    dim3 g(NTOK / 128, NCODE / 128);   // 256 x 32
    score_pass<<<g, 256, 0, stream>>>(zb, eb, en32, rowmin);

    gather_loss<<<NELEM / 4 / 256, 256, 0, stream>>>(z, emb, rowmin, out, sse);
    hist_kernel<<<NTOK / 256, 256, 0, stream>>>(rowmin, counts);
    finalize<<<1, 256, 0, stream>>>(counts, sse, out);
}

// Round 3
// 352.638 us; speedup vs baseline: 3.4951x; 1.7498x over previous
//
#include <hip/hip_runtime.h>

// ---------------- problem constants ----------------
#define NTOK   32768
#define DIM    512
#define NCODE  4096
#define NELEM  (NTOK*DIM)          // 16777216
#define COMMIT 0.25

// ---------------- ws layout (bytes) ----------------
#define OFF_ZB      0ULL                 // bf16 z: 32768*512*2 = 33554432
#define OFF_EB      33554432ULL          // bf16 emb: 4096*512*2 = 4194304
#define OFF_EN32    37748736ULL          // float[4096]
#define OFF_ROWMIN  37765120ULL          // u64[32768]  (packed f32key|code)
#define OFF_COUNTS  38027264ULL          // u32[4096] = 16384
#define OFF_SSE     38043648ULL          // double[256] = 2048
#define INIT0_BYTES (16384 + 2048)

typedef __bf16 bf16x8 __attribute__((ext_vector_type(8)));
typedef float  floatx4 __attribute__((ext_vector_type(4)));

#define GLOBAL_AS __attribute__((address_space(1)))
#define LDS_AS    __attribute__((address_space(3)))

// ---------------- helpers ----------------
__device__ __forceinline__ unsigned short f2bf(float f) {
    unsigned u = __float_as_uint(f);
    u += 0x7FFFu + ((u >> 16) & 1u);   // RNE
    return (unsigned short)(u >> 16);
}
__device__ __forceinline__ unsigned f2key(float f) {   // order-preserving f32 -> u32
    unsigned u = __float_as_uint(f);
    return (u & 0x80000000u) ? ~u : (u | 0x80000000u);
}
__device__ __forceinline__ void gld16(const void* g, void* l) {
    // async global->LDS, 16B/lane; LDS dest = wave-uniform base + lane*16
    __builtin_amdgcn_global_load_lds((const GLOBAL_AS unsigned int*)g,
                                     (LDS_AS unsigned int*)l, 16, 0, 0);
}

// ---------------- 1. fp32 -> bf16 conversion ----------------
__global__ void conv_kernel(const float* __restrict__ z, const float* __restrict__ e,
                            unsigned short* __restrict__ zb, unsigned short* __restrict__ eb) {
    const int ZF4 = NELEM / 4;            // 4194304
    const int TF4 = ZF4 + (NCODE*DIM)/4;  // + 524288
    int i = blockIdx.x * blockDim.x + threadIdx.x;
    if (i >= TF4) return;
    const float4* src; unsigned short* dst; int j;
    if (i < ZF4) { src = (const float4*)z; dst = zb; j = i; }
    else         { src = (const float4*)e; dst = eb; j = i - ZF4; }
    float4 v = src[j];
    ushort4 o; o.x = f2bf(v.x); o.y = f2bf(v.y); o.z = f2bf(v.z); o.w = f2bf(v.w);
    ((ushort4*)dst)[j] = o;
}

// ---------------- 2. ||e_k||^2 (f32, double-accumulated) ----------------
__global__ void enorm_kernel(const float* __restrict__ emb, float* __restrict__ en32) {
    int gw = (blockIdx.x * blockDim.x + threadIdx.x) >> 6;   // wave id = code
    int lane = threadIdx.x & 63;
    if (gw >= NCODE) return;
    const float4* p = (const float4*)(emb + (size_t)gw * DIM);
    float4 a = p[lane * 2], b = p[lane * 2 + 1];
    double s = (double)a.x*a.x + (double)a.y*a.y + (double)a.z*a.z + (double)a.w*a.w
             + (double)b.x*b.x + (double)b.y*b.y + (double)b.z*b.z + (double)b.w*b.w;
    for (int off = 32; off; off >>= 1) s += __shfl_down(s, off);
    if (lane == 0) en32[gw] = (float)s;
}

// ---------------- 3. single MFMA score pass -> packed rowmin ----------------
// tile 128x128, BK=64, 4 waves 2x2, each wave 4x4 of 16x16x32 MFMAs.
// LDS layout XOR-swizzled at 16B granularity: LDS[r][c] = G[r][c ^ (r&7)]
// (swizzle applied on global src addr — global_load_lds LDS dest is lane-fixed).
// Fragment reads then hit 8 distinct 4-bank groups per quad-group -> 2-way (free).
__global__ __launch_bounds__(256)
void score_pass(const unsigned short* __restrict__ zb, const unsigned short* __restrict__ eb,
                const float* __restrict__ en32,
                unsigned long long* __restrict__ rowmin,
                unsigned* __restrict__ counts) {
    __shared__ unsigned short sA[128 * 64];
    __shared__ unsigned short sB[128 * 64];
    const int tid = threadIdx.x;
    const int row0 = blockIdx.x * 128;   // token tile
    const int col0 = blockIdx.y * 128;   // code tile
    const int wv = tid >> 6, ln = tid & 63;
    const int wm = wv >> 1, wn = wv & 1;
    const int l15 = ln & 15, quad = ln >> 4;

    floatx4 acc[4][4] = {};

    const int lrow = ln >> 3;                  // 0..7 : lane's row within 8-row chunk
    const int lcol = ((ln & 7) ^ lrow) * 16;   // swizzled source byte offset (rowA&7 == lrow)

    for (int ks = 0; ks < DIM; ks += 64) {
        __syncthreads();                 // previous iter's ds_reads done
#pragma unroll
        for (int r = 0; r < 4; r++) {
            int ch = wv * 4 + r;         // 0..15, wave-uniform
            int rowA = ch * 8 + lrow;    // 0..127
            gld16((const char*)&zb[(size_t)(row0 + rowA) * DIM + ks] + lcol,
                  (char*)&sA[ch * 512]);
            gld16((const char*)&eb[(size_t)(col0 + rowA) * DIM + ks] + lcol,
                  (char*)&sB[ch * 512]);
        }
        __syncthreads();                 // vmcnt drained before barrier -> loads landed
#pragma unroll
        for (int kk = 0; kk < 2; kk++) {
            bf16x8 af[4], bfr[4];
#pragma unroll
            for (int i = 0; i < 4; i++) {
                int m = wm * 64 + i * 16 + l15;      // A[m][k]: m=lane&15, k=quad*8+j
                int ca = (kk * 4 + quad) ^ (m & 7);  // un-swizzle chunk
                af[i]  = *(const bf16x8*)(&sA[m * 64 + ca * 8]);
                int n = wn * 64 + i * 16 + l15;      // B[k][n]: n=lane&15, k=quad*8+j
                int cb = (kk * 4 + quad) ^ (n & 7);
                bfr[i] = *(const bf16x8*)(&sB[n * 64 + cb * 8]);
            }
#pragma unroll
            for (int i = 0; i < 4; i++)
#pragma unroll
                for (int j = 0; j < 4; j++)
                    acc[i][j] = __builtin_amdgcn_mfma_f32_16x16x32_bf16(af[i], bfr[j], acc[i][j], 0, 0, 0);
        }
    }

    // C/D layout: col = lane&15, row = quad*4 + reg  [verified m89/m91]
#pragma unroll
    for (int i = 0; i < 4; i++) {
#pragma unroll
        for (int reg = 0; reg < 4; reg++) {
            unsigned long long best = ~0ULL;
#pragma unroll
            for (int j = 0; j < 4; j++) {
                int n = col0 + wn * 64 + j * 16 + l15;
                float s = en32[n] - 2.0f * acc[i][j][reg];
                unsigned long long p = ((unsigned long long)f2key(s) << 32) | (unsigned)n;
                best = best < p ? best : p;
            }
#pragma unroll
            for (int off = 1; off < 16; off <<= 1) {
                unsigned long long o = __shfl_xor(best, off);
                best = best < o ? best : o;
            }
            if (l15 == 0) {
                int m = row0 + wm * 64 + i * 16 + quad * 4 + reg;
                atomicMin(&rowmin[m], best);
            }
        }
    }
    (void)counts;
}

// ---------------- 4. gather + STE output + sse + hist -------------
__global__ void gather_loss(const float* __restrict__ z, const float* __restrict__ emb,
                            const unsigned long long* __restrict__ rowmin,
                            float* __restrict__ out, double* __restrict__ sse,
                            unsigned* __restrict__ counts) {
    int i = blockIdx.x * blockDim.x + threadIdx.x;   // f4 index, 4194304 total
    float4 zv = ((const float4*)z)[i];
    int row = i >> 7, col = i & 127;
    unsigned code = (unsigned)(rowmin[row] & 0xFFFFFFFFULL);
    if (col == 0) atomicAdd(&counts[code], 1u);      // fused histogram: one lane per row
    float4 q = ((const float4*)emb)[code * 128 + col];
    float4 dv = make_float4(q.x - zv.x, q.y - zv.y, q.z - zv.z, q.w - zv.w);
    float4 o  = make_float4(zv.x + dv.x, zv.y + dv.y, zv.z + dv.z, zv.w + dv.w);
    ((float4*)out)[i] = o;
    double loc = (double)dv.x*dv.x + (double)dv.y*dv.y + (double)dv.z*dv.z + (double)dv.w*dv.w;
    for (int off = 32; off; off >>= 1) loc += __shfl_down(loc, off);
    __shared__ double sw[4];
    if ((threadIdx.x & 63) == 0) sw[threadIdx.x >> 6] = loc;
    __syncthreads();
    if (threadIdx.x == 0)
        atomicAdd(&sse[blockIdx.x & 255], sw[0] + sw[1] + sw[2] + sw[3]);  // 256 slots: kill contention
}

// ---------------- 5. losses + perplexity -------------
__global__ void finalize(const unsigned* __restrict__ counts, const double* __restrict__ sse,
                         float* __restrict__ out) {
    __shared__ double sh[256], sv[256];
    double h = 0.0;
    for (int b = threadIdx.x; b < NCODE; b += 256) {
        double p = (double)counts[b] / (double)NTOK;
        h += p * log(p + 1e-10);
    }
    sh[threadIdx.x] = h;
    sv[threadIdx.x] = sse[threadIdx.x];
    __syncthreads();
    for (int off = 128; off > 0; off >>= 1) {
        if (threadIdx.x < off) {
            sh[threadIdx.x] += sh[threadIdx.x + off];
            sv[threadIdx.x] += sv[threadIdx.x + off];
        }
        __syncthreads();
    }
    if (threadIdx.x == 0) {
        out[NELEM]     = (float)((1.0 + COMMIT) * sv[0] / (double)NELEM);  // vq_loss
        out[NELEM + 1] = (float)exp(-sh[0]);                                // perplexity
    }
}

// ---------------- launch ----------------
extern "C" void kernel_launch(void* const* d_in, const int* in_sizes, int n_in,
                              void* d_out, int out_size, void* d_ws, size_t ws_size,
                              hipStream_t stream) {
    const float* z   = (const float*)d_in[0];
    const float* emb = (const float*)d_in[1];
    float* out = (float*)d_out;
    char* ws = (char*)d_ws;

    unsigned short* zb = (unsigned short*)(ws + OFF_ZB);
    unsigned short* eb = (unsigned short*)(ws + OFF_EB);
    float*    en32   = (float*)(ws + OFF_EN32);
    unsigned long long* rowmin = (unsigned long long*)(ws + OFF_ROWMIN);
    unsigned* counts = (unsigned*)(ws + OFF_COUNTS);
    double*   sse    = (double*)(ws + OFF_SSE);

    // init: rowmin -> 0xFF (u64 max); counts & sse -> 0
    hipMemsetAsync(ws + OFF_ROWMIN, 0xFF, 262144, stream);
    hipMemsetAsync(ws + OFF_COUNTS, 0x00, INIT0_BYTES, stream);

    conv_kernel<<<(NELEM/4 + (NCODE*DIM)/4 + 255) / 256, 256, 0, stream>>>(z, emb, zb, eb);
    enorm_kernel<<<(NCODE * 64) / 256, 256, 0, stream>>>(emb, en32);

    dim3 g(NTOK / 128, NCODE / 128);   // 256 x 32
    score_pass<<<g, 256, 0, stream>>>(zb, eb, en32, rowmin, counts);

    gather_loss<<<NELEM / 4 / 256, 256, 0, stream>>>(z, emb, rowmin, out, sse, counts);
    finalize<<<1, 256, 0, stream>>>(counts, sse, out);
}